// Round 11
// baseline (994.045 us; speedup 1.0000x reference)
//
#include <hip/hip_runtime.h>
#include <hip/hip_bf16.h>

#define M_DIM 8192
#define N_DIM 4096
#define K_DIM 4096

using bf16x8 = __attribute__((ext_vector_type(8))) short;
using f32x4  = __attribute__((ext_vector_type(4))) float;

// ---------- fp32 -> bf16 (RNE via bit math) ----------
__device__ __forceinline__ unsigned short f2bf(float f) {
    unsigned int u = __float_as_uint(f);
    unsigned int r = u + 0x7fffu + ((u >> 16) & 1u);
    return (unsigned short)(r >> 16);
}

// Single fused conversion: x (n4x float4s) then w (n4w float4s) into ws.
__global__ void cvt_both_f32_to_bf16(const float* __restrict__ x,
                                     const float* __restrict__ w,
                                     unsigned short* __restrict__ ws,
                                     int n4x, int n4w) {
    int i = blockIdx.x * blockDim.x + threadIdx.x;
    const int stride = gridDim.x * blockDim.x;
    const int total = n4x + n4w;
    uint2* dx = reinterpret_cast<uint2*>(ws);
    uint2* dw = reinterpret_cast<uint2*>(ws) + n4x;
    for (; i < total; i += stride) {
        const bool isX = i < n4x;
        const float4* s4 = isX ? reinterpret_cast<const float4*>(x)
                               : reinterpret_cast<const float4*>(w);
        const int j = isX ? i : i - n4x;
        float4 v = s4[j];
        uint2 o;
        o.x = (unsigned)f2bf(v.x) | ((unsigned)f2bf(v.y) << 16);
        o.y = (unsigned)f2bf(v.z) | ((unsigned)f2bf(v.w) << 16);
        (isX ? dx : dw)[j] = o;
    }
}

// ---------- async global->LDS, 16B per lane ----------
__device__ __forceinline__ void gload16(const unsigned short* g, char* l) {
    __builtin_amdgcn_global_load_lds(
        (const __attribute__((address_space(1))) void*)g,
        (__attribute__((address_space(3))) void*)l, 16, 0, 0);
}

// ============================================================================
// 256x256 bf16 MFMA GEMM — round 11: 4 waves x 128x128 per wave.
// R6 was LDS-BW-bound (reads 192KB + writes 64KB per tile = 3012 cyc floor >
// MFMA 2483). 2x2 wave grid: each A/B panel read by 2 waves -> reads 128KB,
// LDS floor 2259 < MFMA 2483 -> MFMA-bound. 1 wave/SIMD; latency hidden by
// the R6 cross-barrier register pipeline (MFMA never waits on lgkm).
//
// Regions (16KB): A-q = M-rows [q*128,+128) of tile, row stride 128B; B-p =
// N-cols [p*128,+128). Wave (wm,wn) reads ONLY A[wm], B[wn]; panel halves
// h0 = frags 0-3 (rows 0-63), h1 = frags 4-7.
// Reads: av.h0(t) at I4(t-1) [from buf(t)], bv1=B.h1(t) at I1(t),
//        av.h1(t) at I2(t), bvY=B.h0(t+1) at I3(t) [from nbuf].
// Region deaths: B(buf) dead end-I1(t) (h1 read); A(buf) dead end-I2(t).
// Stage schedule: I1: A1(t+1)->nbuf; I2: B0(t+2)->buf; I3: A0(t+2)->buf;
//                 I4: B1(t+2)->buf.   (every stage after its slot's death)
// vmcnt (4 loads per stage call), coverage = calls issued after the staged
// region, at the wait gating its first read:
//   bv1(t):  B1(t)@I4(t-2) -> 4 calls after at W4(t-1) -> vmcnt(16)
//   av.h1(t): A1(t)@I1(t-1) -> 4 calls at W1(t) -> vmcnt(16)  [A0 older]
//   bvY(t+1): B0(t+1)@I2(t-1) -> 4 calls at W2(t) -> vmcnt(16)
//   av.h0(t+1): A1(t+1)@I1(t) -> 2 calls at W3(t) -> vmcnt(8) [A0 older]
// Prologue: stage t0 x4 + {A0,B0,B1}(t1); vmcnt(12) lands t0; pre-read
// av.h0(0), bvX=B.h0(0). Tail stages wrapped kt (dummy -> dead slots; dummy
// reads at I3/I4(NT-1) are never consumed by MFMA). vmcnt(0) after loop.
// ============================================================================
__global__ __launch_bounds__(256, 1) void gemm_bf16_256_w4(
        const unsigned short* __restrict__ xb,   // [M,K] bf16 bits
        const unsigned short* __restrict__ wb,   // [N,K] bf16 bits
        const float* __restrict__ bias,          // [N]
        float* __restrict__ out) {               // [M,N]
    extern __shared__ char lds[];
    char* ldsA = lds;           // [2 buf][2 q][16384 B]
    char* ldsB = lds + 65536;   // [2 buf][2 p][16384 B]

    // L2-aware XCD chunk map (round 4: FETCH 549->201 MB)
    const int bid = blockIdx.x;
    const int xcd = bid & 7;
    const int c   = bid >> 3;                 // 0..63
    const int tm  = (xcd >> 1) * 8 + (c & 7); // 0..31
    const int tn  = (xcd & 1) * 8 + (c >> 3); // 0..15
    const int r0 = tm * 256;
    const int c0 = tn * 256;

    const int tid  = threadIdx.x;
    const int lane = tid & 63;
    const int wave = tid >> 6;        // 0..3
    const int wm = wave >> 1;         // 0..1  (128-row half)
    const int wn = wave & 1;          // 0..1  (128-col half)
    const int lr = lane & 15;
    const int t4 = lane >> 4;

    // --- ds_read bases (bytes), T2 swizzle (row&7 == lr&7) ---
    const int swz = (lr & 7) << 4;
    int cb[2];
#pragma unroll
    for (int ks = 0; ks < 2; ++ks)
        cb[ks] = (ks * 64 + t4 * 16) ^ swz;
    const int aBase = wm * 16384 + lr * 128;
    const int bBase = wn * 16384 + lr * 128;

    // --- staging: wave-uniform LDS dest (HW adds lane*16), inverse-swizzled
    //     global source; one stage call = one 16KB region = 4 loads/thread ---
    const int rowInBlk = lane >> 3;                       // 0..7
    const int sChunk   = ((lane & 7) ^ rowInBlk) * 8;     // element offset

    auto STAGE_A = [&](int q, int kt, int nb) {
#pragma unroll
        for (int l = 0; l < 4; ++l)
            gload16(xb + (r0 + q * 128 + wave * 32 + l * 8 + rowInBlk) * K_DIM
                       + sChunk + kt * 64,
                    ldsA + nb * 32768 + q * 16384 + wave * 4096 + l * 1024);
    };
    auto STAGE_B = [&](int p, int kt, int nb) {
#pragma unroll
        for (int l = 0; l < 4; ++l)
            gload16(wb + (c0 + p * 128 + wave * 32 + l * 8 + rowInBlk) * K_DIM
                       + sChunk + kt * 64,
                    ldsB + nb * 32768 + p * 16384 + wave * 4096 + l * 1024);
    };

    f32x4 acc[8][8];
#pragma unroll
    for (int i = 0; i < 8; ++i)
#pragma unroll
        for (int j = 0; j < 8; ++j)
            acc[i][j] = (f32x4){0.f, 0.f, 0.f, 0.f};

    bf16x8 av[4][2], bvX[4][2], bvY[4][2], bv1[4][2];

#define LOAD_AH(H, BUF)                                                        \
    _Pragma("unroll") for (int m = 0; m < 4; ++m)                              \
    _Pragma("unroll") for (int ks = 0; ks < 2; ++ks)                           \
        av[m][ks] = *(const bf16x8*)(ldsA + (BUF) * 32768 + aBase              \
                                     + ((H) * 4 + m) * 2048 + cb[ks]);

#define LOAD_BH(H, BUF, BV)                                                    \
    _Pragma("unroll") for (int n = 0; n < 4; ++n)                              \
    _Pragma("unroll") for (int ks = 0; ks < 2; ++ks)                           \
        (BV)[n][ks] = *(const bf16x8*)(ldsB + (BUF) * 32768 + bBase            \
                                       + ((H) * 4 + n) * 2048 + cb[ks]);

#define MFMA_QUAD(MH, NH, BV)                                                  \
    do {                                                                       \
        __builtin_amdgcn_s_setprio(1);                                         \
        _Pragma("unroll") for (int m = 0; m < 4; ++m)                          \
        _Pragma("unroll") for (int n = 0; n < 4; ++n)                          \
        _Pragma("unroll") for (int ks = 0; ks < 2; ++ks)                       \
            acc[(MH) * 4 + m][(NH) * 4 + n] =                                  \
                __builtin_amdgcn_mfma_f32_16x16x32_bf16(                       \
                    av[m][ks], (BV)[n][ks], acc[(MH) * 4 + m][(NH) * 4 + n],   \
                    0, 0, 0);                                                  \
        __builtin_amdgcn_s_setprio(0);                                         \
    } while (0)

    const int NT = K_DIM / 64;   // 64

#define TILE_BODY(T, BUF, XV, YV)                                              \
    do {                                                                       \
        const int nb_  = (BUF) ^ 1;                                           \
        const int kt1_ = ((T) + 1) & (NT - 1);                                 \
        const int kt2_ = ((T) + 2) & (NT - 1);                                 \
        /* I1: MFMA h0xh0 (av,X); read bv1=B.h1(t); stage A1(t+1)->nbuf */     \
        STAGE_A(1, kt1_, nb_);                                                 \
        LOAD_BH(1, (BUF), bv1);                                                \
        MFMA_QUAD(0, 0, XV);                                                   \
        asm volatile("s_waitcnt vmcnt(16)\n\ts_barrier" ::: "memory");         \
        /* I2: MFMA h0xh1 (av,bv1); overlay av<-A.h1(t); stage B0(t+2) */      \
        STAGE_B(0, kt2_, (BUF));                                               \
        MFMA_QUAD(0, 1, bv1);                                                  \
        LOAD_AH(1, (BUF));                                                     \
        asm volatile("s_waitcnt vmcnt(16)\n\ts_barrier" ::: "memory");         \
        /* I3: MFMA h1xh1; read Y<-B.h0(t+1) from nbuf; stage A0(t+2) */       \
        STAGE_A(0, kt2_, (BUF));                                               \
        LOAD_BH(0, nb_, YV);                                                   \
        MFMA_QUAD(1, 1, bv1);                                                  \
        asm volatile("s_waitcnt vmcnt(8)\n\ts_barrier" ::: "memory");          \
        /* I4: MFMA h1xh0 (av,X); overlay av<-A.h0(t+1); stage B1(t+2) */      \
        STAGE_B(1, kt2_, (BUF));                                               \
        MFMA_QUAD(1, 0, XV);                                                   \
        LOAD_AH(0, nb_);                                                       \
        asm volatile("s_waitcnt vmcnt(16)\n\ts_barrier" ::: "memory");         \
    } while (0)

    // --- prologue: t0 {A0,A1,B0,B1} + t1 {A0,B0,B1}; vmcnt(12) lands t0 ---
    STAGE_A(0, 0, 0);
    STAGE_A(1, 0, 0);
    STAGE_B(0, 0, 0);
    STAGE_B(1, 0, 0);
    STAGE_A(0, 1, 1);
    STAGE_B(0, 1, 1);
    STAGE_B(1, 1, 1);
    asm volatile("s_waitcnt vmcnt(12)\n\ts_barrier" ::: "memory");
    LOAD_AH(0, 0);          // av  <- A.h0(0)
    LOAD_BH(0, 0, bvX);     // bvX <- B.h0(0)

    for (int tt = 0; tt < NT / 2; ++tt) {
        TILE_BODY(2 * tt,     0, bvX, bvY);
        TILE_BODY(2 * tt + 1, 1, bvY, bvX);
    }
    asm volatile("s_waitcnt vmcnt(0)" ::: "memory");   // drain dummy stages

    // --- epilogue: C/D layout col=lane&15, row=t4*4+j ---
#pragma unroll
    for (int ni = 0; ni < 8; ++ni) {
        const int col = c0 + wn * 128 + ni * 16 + lr;
        const float bvs = bias[col];
#pragma unroll
        for (int mi = 0; mi < 8; ++mi) {
            const int row0 = r0 + wm * 128 + mi * 16 + t4 * 4;
#pragma unroll
            for (int j = 0; j < 4; ++j)
                out[(row0 + j) * N_DIM + col] = acc[mi][ni][j] + bvs;
        }
    }
#undef TILE_BODY
#undef MFMA_QUAD
#undef LOAD_AH
#undef LOAD_BH
}

// ============================================================================
// Proven round-1 128x128 kernel — runtime fallback if dynamic LDS
// cannot be enabled.
// ============================================================================
__global__ __launch_bounds__(256) void gemm_bf16_mfma(
        const unsigned short* __restrict__ xb,
        const unsigned short* __restrict__ wb,
        const float* __restrict__ bias,
        float* __restrict__ out) {
    __shared__ unsigned short sA[128 * 64];
    __shared__ unsigned short sB[128 * 64];

    const int nwg = (M_DIM / 128) * (N_DIM / 128);
    const int q = nwg / 8;
    int bid = blockIdx.x;
    int bid2 = (bid & 7) * q + (bid >> 3);
    const int tm = bid2 & 63;
    const int tn = bid2 >> 6;
    const int r0 = tm * 128;
    const int c0 = tn * 128;

    const int tid  = threadIdx.x;
    const int lane = tid & 63;
    const int wave = tid >> 6;
    const int wr = wave >> 1;
    const int wc = wave & 1;
    const int lr = lane & 15;
    const int t  = lane >> 4;

    int aoff[2][4], boff[2][4];
#pragma unroll
    for (int m = 0; m < 4; ++m) {
        int rowA = wr * 64 + m * 16 + lr;
        int swA  = (rowA & 7) << 4;
        int rowB = wc * 64 + m * 16 + lr;
        int swB  = (rowB & 7) << 4;
#pragma unroll
        for (int kk = 0; kk < 2; ++kk) {
            int cb = kk * 64 + t * 16;
            aoff[kk][m] = rowA * 64 + ((cb ^ swA) >> 1);
            boff[kk][m] = rowB * 64 + ((cb ^ swB) >> 1);
        }
    }

    const int sRow   = lane >> 3;
    const int sChunk = (lane & 7) ^ sRow;
    int aSrc[4], bSrc[4];
    char* ldsA[4];
    char* ldsB[4];
#pragma unroll
    for (int r = 0; r < 4; ++r) {
        int row = r * 32 + wave * 8 + sRow;
        aSrc[r] = (r0 + row) * K_DIM + sChunk * 8;
        bSrc[r] = (c0 + row) * K_DIM + sChunk * 8;
        ldsA[r] = (char*)sA + (r * 4 + wave) * 1024;
        ldsB[r] = (char*)sB + (r * 4 + wave) * 1024;
    }

    f32x4 acc[4][4];
#pragma unroll
    for (int m = 0; m < 4; ++m)
#pragma unroll
        for (int n = 0; n < 4; ++n)
            acc[m][n] = (f32x4){0.f, 0.f, 0.f, 0.f};

    for (int kt = 0; kt < K_DIM / 64; ++kt) {
        const int ko = kt * 64;
#pragma unroll
        for (int r = 0; r < 4; ++r) {
            gload16(xb + aSrc[r] + ko, ldsA[r]);
            gload16(wb + bSrc[r] + ko, ldsB[r]);
        }
        __syncthreads();
#pragma unroll
        for (int kk = 0; kk < 2; ++kk) {
            bf16x8 av[4], bv[4];
#pragma unroll
            for (int m = 0; m < 4; ++m)
                av[m] = *reinterpret_cast<const bf16x8*>(sA + aoff[kk][m]);
#pragma unroll
            for (int n = 0; n < 4; ++n)
                bv[n] = *reinterpret_cast<const bf16x8*>(sB + boff[kk][n]);
#pragma unroll
            for (int m = 0; m < 4; ++m)
#pragma unroll
                for (int n = 0; n < 4; ++n)
                    acc[m][n] = __builtin_amdgcn_mfma_f32_16x16x32_bf16(
                        av[m], bv[n], acc[m][n], 0, 0, 0);
        }
        __syncthreads();
    }

#pragma unroll
    for (int n = 0; n < 4; ++n) {
        const int col = c0 + wc * 64 + n * 16 + lr;
        const float bv = bias[col];
#pragma unroll
        for (int m = 0; m < 4; ++m) {
            const int row0 = r0 + wr * 64 + m * 16 + t * 4;
#pragma unroll
            for (int j = 0; j < 4; ++j)
                out[(row0 + j) * N_DIM + col] = acc[m][n][j] + bv;
        }
    }
}

// ---------- fp32 fallback (only if ws too small) ----------
__global__ void fallback_gemm_f32(const float* __restrict__ x,
                                  const float* __restrict__ w,
                                  const float* __restrict__ bias,
                                  float* __restrict__ out) {
    __shared__ float sX[2][4096];
    const int tid = threadIdx.x;
    const int col = blockIdx.x * 256 + tid;
    const int row0 = blockIdx.y * 2;
    for (int i = tid * 4; i < 8192; i += 1024) {
        int r = i >> 12, c = i & 4095;
        *(float4*)&sX[r][c] = *(const float4*)&x[(size_t)(row0 + r) * 4096 + c];
    }
    __syncthreads();
    const float4* wrow = (const float4*)&w[(size_t)col * 4096];
    float a0 = 0.f, a1 = 0.f;
    for (int k4 = 0; k4 < 1024; ++k4) {
        float4 wv = wrow[k4];
        int k = k4 << 2;
        a0 += wv.x * sX[0][k] + wv.y * sX[0][k + 1] + wv.z * sX[0][k + 2] + wv.w * sX[0][k + 3];
        a1 += wv.x * sX[1][k] + wv.y * sX[1][k + 1] + wv.z * sX[1][k + 2] + wv.w * sX[1][k + 3];
    }
    float bv = bias[col];
    out[(size_t)row0 * 4096 + col] = a0 + bv;
    out[(size_t)(row0 + 1) * 4096 + col] = a1 + bv;
}

extern "C" void kernel_launch(void* const* d_in, const int* in_sizes, int n_in,
                              void* d_out, int out_size, void* d_ws, size_t ws_size,
                              hipStream_t stream) {
    const float* x    = (const float*)d_in[0];
    const float* w    = (const float*)d_in[1];
    const float* bias = (const float*)d_in[2];
    float* out = (float*)d_out;

    const size_t nX = (size_t)M_DIM * K_DIM;
    const size_t nW = (size_t)N_DIM * K_DIM;
    const size_t need = (nX + nW) * sizeof(unsigned short);

    if (ws_size >= need) {
        unsigned short* xb = (unsigned short*)d_ws;
        unsigned short* wb = xb + nX;
        cvt_both_f32_to_bf16<<<3072, 256, 0, stream>>>(
            x, w, (unsigned short*)d_ws, (int)(nX / 4), (int)(nW / 4));
        hipError_t e = hipFuncSetAttribute(
            (const void*)gemm_bf16_256_w4,
            hipFuncAttributeMaxDynamicSharedMemorySize, 131072);
        if (e == hipSuccess) {
            gemm_bf16_256_w4<<<(M_DIM / 256) * (N_DIM / 256), 256, 131072, stream>>>(
                xb, wb, bias, out);
        } else {
            gemm_bf16_mfma<<<(M_DIM / 128) * (N_DIM / 128), 256, 0, stream>>>(
                xb, wb, bias, out);
        }
    } else {
        fallback_gemm_f32<<<dim3(N_DIM / 256, M_DIM / 2), 256, 0, stream>>>(x, w, bias, out);
    }
}

// Round 12
// 277.853 us; speedup vs baseline: 3.5776x; 3.5776x over previous
//
#include <hip/hip_runtime.h>
#include <hip/hip_bf16.h>

#define M_DIM 8192
#define N_DIM 4096
#define K_DIM 4096

using bf16x8 = __attribute__((ext_vector_type(8))) short;
using f32x4  = __attribute__((ext_vector_type(4))) float;

// ---------- fp32 -> bf16 (RNE via bit math) ----------
__device__ __forceinline__ unsigned short f2bf(float f) {
    unsigned int u = __float_as_uint(f);
    unsigned int r = u + 0x7fffu + ((u >> 16) & 1u);
    return (unsigned short)(r >> 16);
}

// Single fused conversion: x (n4x float4s) then w (n4w float4s) into ws.
__global__ void cvt_both_f32_to_bf16(const float* __restrict__ x,
                                     const float* __restrict__ w,
                                     unsigned short* __restrict__ ws,
                                     int n4x, int n4w) {
    int i = blockIdx.x * blockDim.x + threadIdx.x;
    const int stride = gridDim.x * blockDim.x;
    const int total = n4x + n4w;
    uint2* dx = reinterpret_cast<uint2*>(ws);
    uint2* dw = reinterpret_cast<uint2*>(ws) + n4x;
    for (; i < total; i += stride) {
        const bool isX = i < n4x;
        const float4* s4 = isX ? reinterpret_cast<const float4*>(x)
                               : reinterpret_cast<const float4*>(w);
        const int j = isX ? i : i - n4x;
        float4 v = s4[j];
        uint2 o;
        o.x = (unsigned)f2bf(v.x) | ((unsigned)f2bf(v.y) << 16);
        o.y = (unsigned)f2bf(v.z) | ((unsigned)f2bf(v.w) << 16);
        (isX ? dx : dw)[j] = o;
    }
}

// ---------- async global->LDS, 16B per lane ----------
__device__ __forceinline__ void gload16(const unsigned short* g, char* l) {
    __builtin_amdgcn_global_load_lds(
        (const __attribute__((address_space(1))) void*)g,
        (__attribute__((address_space(3))) void*)l, 16, 0, 0);
}

// ============================================================================
// 256x256 bf16 MFMA GEMM — round 12: R8's m201-style same-phase structure
// WITHOUT sched_barrier(0). Clean A/B: R8 regression hypothesis = the fence
// pinned hipcc's scheduler (rule #18 applies only to inline-asm ds_reads;
// ours are compiler-emitted). Everything else identical to R8 (which passed
// refcheck): stage schedule, vmcnt ledger, swizzle, L2 map.
//
// Per phase: {ds_read operands; stage} -> s_barrier; lgkmcnt(0) -> 16 MFMA
// (setprio-wrapped) -> s_barrier.
// Stage schedule (during tile t): I1: A1(t+1)->nbuf, I2: A0(t+2)->buf,
// I3: B0(t+2)->buf, I4: B1(t+2)->buf.
// Reads (same-phase): {A0(t),B0(t)}@I1, B1(t)@I2, A1(t)@I3, none@I4.
// ONE vmcnt(6) per tile at I4's first barrier (coverage audited in R8).
// Prologue t0 x4 + t1 x3, vmcnt(6). Tail stages wrapped kt (dummy).
// ============================================================================
__global__ __launch_bounds__(512, 2) void gemm_bf16_256_8ph(
        const unsigned short* __restrict__ xb,   // [M,K] bf16 bits
        const unsigned short* __restrict__ wb,   // [N,K] bf16 bits
        const float* __restrict__ bias,          // [N]
        float* __restrict__ out) {               // [M,N]
    extern __shared__ char lds[];
    char* ldsA = lds;           // [2 buf][2 q][16384 B]
    char* ldsB = lds + 65536;   // [2 buf][2 p][16384 B]

    // L2-aware XCD chunk map (round 4: FETCH 549->201 MB)
    const int bid = blockIdx.x;
    const int xcd = bid & 7;
    const int c   = bid >> 3;                 // 0..63
    const int tm  = (xcd >> 1) * 8 + (c & 7); // 0..31
    const int tn  = (xcd & 1) * 8 + (c >> 3); // 0..15
    const int r0 = tm * 256;
    const int c0 = tn * 256;

    const int tid  = threadIdx.x;
    const int lane = tid & 63;
    const int wave = tid >> 6;        // 0..7
    const int wm = wave >> 2;         // 0..1  (128-row half)
    const int wn = wave & 3;          // 0..3  (64-col strip)
    const int lr = lane & 15;
    const int t4 = lane >> 4;

    // --- ds_read offsets (bytes within one 16KB region), T2-swizzled ---
    int aRd[4][2], bRd[2][2];
    const int swz = (lr & 7) << 4;
#pragma unroll
    for (int ks = 0; ks < 2; ++ks) {
        const int cb = (ks * 64 + t4 * 16) ^ swz;
#pragma unroll
        for (int m = 0; m < 4; ++m)
            aRd[m][ks] = (wm * 64 + m * 16 + lr) * 128 + cb;
#pragma unroll
        for (int n = 0; n < 2; ++n)
            bRd[n][ks] = (wn * 32 + n * 16 + lr) * 128 + cb;
    }

    // --- staging: wave-uniform LDS dest (HW adds lane*16), inverse-swizzled
    //     global source ---
    const int rowInBlk = lane >> 3;                       // 0..7
    const int sChunk   = ((lane & 7) ^ rowInBlk) * 8;     // element offset
    int aSrcB[2], bSrcB[2], dstOff[2];
#pragma unroll
    for (int l = 0; l < 2; ++l) {
        const int R0 = wave * 16 + l * 8;                 // lds row base 0..120
        aSrcB[l] = (r0 + (R0 >> 6) * 128 + (R0 & 63) + rowInBlk) * K_DIM + sChunk;
        bSrcB[l] = (c0 + (R0 >> 5) * 64  + (R0 & 31) + rowInBlk) * K_DIM + sChunk;
        dstOff[l] = R0 * 128;                             // wave-uniform
    }

    auto STAGE_A = [&](int q, int kt, int nb) {
#pragma unroll
        for (int l = 0; l < 2; ++l)
            gload16(xb + aSrcB[l] + q * 64 * K_DIM + kt * 64,
                    ldsA + nb * 32768 + q * 16384 + dstOff[l]);
    };
    auto STAGE_B = [&](int p, int kt, int nb) {
#pragma unroll
        for (int l = 0; l < 2; ++l)
            gload16(wb + bSrcB[l] + p * 32 * K_DIM + kt * 64,
                    ldsB + nb * 32768 + p * 16384 + dstOff[l]);
    };

    f32x4 acc[8][4];
#pragma unroll
    for (int i = 0; i < 8; ++i)
#pragma unroll
        for (int j = 0; j < 4; ++j)
            acc[i][j] = (f32x4){0.f, 0.f, 0.f, 0.f};

    bf16x8 av[4][2], bv0[2][2], bv1[2][2];

#define MFMA_QUAD(M0, N0, BV)                                                  \
    do {                                                                       \
        __builtin_amdgcn_s_setprio(1);                                         \
        _Pragma("unroll") for (int m = 0; m < 4; ++m)                          \
        _Pragma("unroll") for (int n = 0; n < 2; ++n)                          \
        _Pragma("unroll") for (int ks = 0; ks < 2; ++ks)                       \
            acc[(M0) + m][(N0) + n] = __builtin_amdgcn_mfma_f32_16x16x32_bf16( \
                av[m][ks], BV[n][ks], acc[(M0) + m][(N0) + n], 0, 0, 0);       \
        __builtin_amdgcn_s_setprio(0);                                         \
    } while (0)

#define LOAD_A(Q, BUF)                                                         \
    _Pragma("unroll") for (int m = 0; m < 4; ++m)                              \
    _Pragma("unroll") for (int ks = 0; ks < 2; ++ks)                           \
        av[m][ks] = *(const bf16x8*)(ldsA + (BUF) * 32768 + (Q) * 16384 + aRd[m][ks]);

#define LOAD_B(P, BUF, BV)                                                     \
    _Pragma("unroll") for (int n = 0; n < 2; ++n)                              \
    _Pragma("unroll") for (int ks = 0; ks < 2; ++ks)                           \
        BV[n][ks] = *(const bf16x8*)(ldsB + (BUF) * 32768 + (P) * 16384 + bRd[n][ks]);

    // Phase sync (R12: NO sched_barrier — let hipcc schedule freely).
#define PH_ENTER                                                               \
    asm volatile("s_barrier\n\ts_waitcnt lgkmcnt(0)" ::: "memory")
#define PH_ENTER_VM6                                                           \
    asm volatile("s_waitcnt vmcnt(6)\n\ts_barrier\n\ts_waitcnt lgkmcnt(0)"     \
                 ::: "memory")
#define PH_EXIT asm volatile("s_barrier" ::: "memory")

    const int NT = K_DIM / 64;   // 64

    // --- prologue: t0 {A0,B0,B1,A1} + t1 {A0,B0,B1}; vmcnt(6) lands t0 ---
    STAGE_A(0, 0, 0);
    STAGE_B(0, 0, 0);
    STAGE_B(1, 0, 0);
    STAGE_A(1, 0, 0);
    STAGE_A(0, 1, 1);
    STAGE_B(0, 1, 1);
    STAGE_B(1, 1, 1);
    asm volatile("s_waitcnt vmcnt(6)\n\ts_barrier" ::: "memory");

    for (int t = 0; t < NT; ++t) {
        const int buf = t & 1, nbuf = buf ^ 1;
        const int kt1 = (t + 1) & (NT - 1);
        const int kt2 = (t + 2) & (NT - 1);
        // ---- I1: reads A0(t),B0(t); stage A1(t+1)->nbuf; MFMA q(0,0) ----
        LOAD_A(0, buf);
        LOAD_B(0, buf, bv0);
        STAGE_A(1, kt1, nbuf);
        PH_ENTER;
        MFMA_QUAD(0, 0, bv0);
        PH_EXIT;
        // ---- I2: read B1(t); stage A0(t+2)->buf; MFMA q(0,1) ----
        LOAD_B(1, buf, bv1);
        STAGE_A(0, kt2, buf);
        PH_ENTER;
        MFMA_QUAD(0, 2, bv1);
        PH_EXIT;
        // ---- I3: read A1(t); stage B0(t+2)->buf; MFMA q(1,1) ----
        LOAD_A(1, buf);
        STAGE_B(0, kt2, buf);
        PH_ENTER;
        MFMA_QUAD(4, 2, bv1);
        PH_EXIT;
        // ---- I4: stage B1(t+2)->buf; vmcnt(6); MFMA q(1,0) ----
        STAGE_B(1, kt2, buf);
        PH_ENTER_VM6;
        MFMA_QUAD(4, 0, bv0);
        PH_EXIT;
    }
    asm volatile("s_waitcnt vmcnt(0)" ::: "memory");   // drain dummy stages

    // --- epilogue: C/D layout col=lane&15, row=t4*4+j ---
#pragma unroll
    for (int ni = 0; ni < 4; ++ni) {
        const int col = c0 + wn * 64 + (ni >> 1) * 32 + (ni & 1) * 16 + lr;
        const float bvs = bias[col];
#pragma unroll
        for (int mi = 0; mi < 8; ++mi) {
            const int row0 = r0 + wm * 128 + (mi >> 2) * 64 + (mi & 3) * 16 + t4 * 4;
#pragma unroll
            for (int j = 0; j < 4; ++j)
                out[(row0 + j) * N_DIM + col] = acc[mi][ni][j] + bvs;
        }
    }
#undef PH_ENTER
#undef PH_ENTER_VM6
#undef PH_EXIT
#undef MFMA_QUAD
#undef LOAD_A
#undef LOAD_B
}

// ============================================================================
// Proven round-1 128x128 kernel — runtime fallback if dynamic LDS
// cannot be enabled.
// ============================================================================
__global__ __launch_bounds__(256) void gemm_bf16_mfma(
        const unsigned short* __restrict__ xb,
        const unsigned short* __restrict__ wb,
        const float* __restrict__ bias,
        float* __restrict__ out) {
    __shared__ unsigned short sA[128 * 64];
    __shared__ unsigned short sB[128 * 64];

    const int nwg = (M_DIM / 128) * (N_DIM / 128);
    const int q = nwg / 8;
    int bid = blockIdx.x;
    int bid2 = (bid & 7) * q + (bid >> 3);
    const int tm = bid2 & 63;
    const int tn = bid2 >> 6;
    const int r0 = tm * 128;
    const int c0 = tn * 128;

    const int tid  = threadIdx.x;
    const int lane = tid & 63;
    const int wave = tid >> 6;
    const int wr = wave >> 1;
    const int wc = wave & 1;
    const int lr = lane & 15;
    const int t  = lane >> 4;

    int aoff[2][4], boff[2][4];
#pragma unroll
    for (int m = 0; m < 4; ++m) {
        int rowA = wr * 64 + m * 16 + lr;
        int swA  = (rowA & 7) << 4;
        int rowB = wc * 64 + m * 16 + lr;
        int swB  = (rowB & 7) << 4;
#pragma unroll
        for (int kk = 0; kk < 2; ++kk) {
            int cb = kk * 64 + t * 16;
            aoff[kk][m] = rowA * 64 + ((cb ^ swA) >> 1);
            boff[kk][m] = rowB * 64 + ((cb ^ swB) >> 1);
        }
    }

    const int sRow   = lane >> 3;
    const int sChunk = (lane & 7) ^ sRow;
    int aSrc[4], bSrc[4];
    char* ldsA[4];
    char* ldsB[4];
#pragma unroll
    for (int r = 0; r < 4; ++r) {
        int row = r * 32 + wave * 8 + sRow;
        aSrc[r] = (r0 + row) * K_DIM + sChunk * 8;
        bSrc[r] = (c0 + row) * K_DIM + sChunk * 8;
        ldsA[r] = (char*)sA + (r * 4 + wave) * 1024;
        ldsB[r] = (char*)sB + (r * 4 + wave) * 1024;
    }

    f32x4 acc[4][4];
#pragma unroll
    for (int m = 0; m < 4; ++m)
#pragma unroll
        for (int n = 0; n < 4; ++n)
            acc[m][n] = (f32x4){0.f, 0.f, 0.f, 0.f};

    for (int kt = 0; kt < K_DIM / 64; ++kt) {
        const int ko = kt * 64;
#pragma unroll
        for (int r = 0; r < 4; ++r) {
            gload16(xb + aSrc[r] + ko, ldsA[r]);
            gload16(wb + bSrc[r] + ko, ldsB[r]);
        }
        __syncthreads();
#pragma unroll
        for (int kk = 0; kk < 2; ++kk) {
            bf16x8 av[4], bv[4];
#pragma unroll
            for (int m = 0; m < 4; ++m)
                av[m] = *reinterpret_cast<const bf16x8*>(sA + aoff[kk][m]);
#pragma unroll
            for (int n = 0; n < 4; ++n)
                bv[n] = *reinterpret_cast<const bf16x8*>(sB + boff[kk][n]);
#pragma unroll
            for (int m = 0; m < 4; ++m)
#pragma unroll
                for (int n = 0; n < 4; ++n)
                    acc[m][n] = __builtin_amdgcn_mfma_f32_16x16x32_bf16(
                        av[m], bv[n], acc[m][n], 0, 0, 0);
        }
        __syncthreads();
    }

#pragma unroll
    for (int n = 0; n < 4; ++n) {
        const int col = c0 + wc * 64 + n * 16 + lr;
        const float bv = bias[col];
#pragma unroll
        for (int m = 0; m < 4; ++m) {
            const int row0 = r0 + wr * 64 + m * 16 + t * 4;
#pragma unroll
            for (int j = 0; j < 4; ++j)
                out[(row0 + j) * N_DIM + col] = acc[m][n][j] + bv;
        }
    }
}

// ---------- fp32 fallback (only if ws too small) ----------
__global__ void fallback_gemm_f32(const float* __restrict__ x,
                                  const float* __restrict__ w,
                                  const float* __restrict__ bias,
                                  float* __restrict__ out) {
    __shared__ float sX[2][4096];
    const int tid = threadIdx.x;
    const int col = blockIdx.x * 256 + tid;
    const int row0 = blockIdx.y * 2;
    for (int i = tid * 4; i < 8192; i += 1024) {
        int r = i >> 12, c = i & 4095;
        *(float4*)&sX[r][c] = *(const float4*)&x[(size_t)(row0 + r) * 4096 + c];
    }
    __syncthreads();
    const float4* wrow = (const float4*)&w[(size_t)col * 4096];
    float a0 = 0.f, a1 = 0.f;
    for (int k4 = 0; k4 < 1024; ++k4) {
        float4 wv = wrow[k4];
        int k = k4 << 2;
        a0 += wv.x * sX[0][k] + wv.y * sX[0][k + 1] + wv.z * sX[0][k + 2] + wv.w * sX[0][k + 3];
        a1 += wv.x * sX[1][k] + wv.y * sX[1][k + 1] + wv.z * sX[1][k + 2] + wv.w * sX[1][k + 3];
    }
    float bv = bias[col];
    out[(size_t)row0 * 4096 + col] = a0 + bv;
    out[(size_t)(row0 + 1) * 4096 + col] = a1 + bv;
}

extern "C" void kernel_launch(void* const* d_in, const int* in_sizes, int n_in,
                              void* d_out, int out_size, void* d_ws, size_t ws_size,
                              hipStream_t stream) {
    const float* x    = (const float*)d_in[0];
    const float* w    = (const float*)d_in[1];
    const float* bias = (const float*)d_in[2];
    float* out = (float*)d_out;

    const size_t nX = (size_t)M_DIM * K_DIM;
    const size_t nW = (size_t)N_DIM * K_DIM;
    const size_t need = (nX + nW) * sizeof(unsigned short);

    if (ws_size >= need) {
        unsigned short* xb = (unsigned short*)d_ws;
        unsigned short* wb = xb + nX;
        cvt_both_f32_to_bf16<<<3072, 256, 0, stream>>>(
            x, w, (unsigned short*)d_ws, (int)(nX / 4), (int)(nW / 4));
        hipError_t e = hipFuncSetAttribute(
            (const void*)gemm_bf16_256_8ph,
            hipFuncAttributeMaxDynamicSharedMemorySize, 131072);
        if (e == hipSuccess) {
            gemm_bf16_256_8ph<<<(M_DIM / 256) * (N_DIM / 256), 512, 131072, stream>>>(
                xb, wb, bias, out);
        } else {
            gemm_bf16_mfma<<<(M_DIM / 128) * (N_DIM / 128), 256, 0, stream>>>(
                xb, wb, bias, out);
        }
    } else {
        fallback_gemm_f32<<<dim3(N_DIM / 256, M_DIM / 2), 256, 0, stream>>>(x, w, bias, out);
    }
}

// Round 14
// 250.671 us; speedup vs baseline: 3.9655x; 1.1084x over previous
//
#include <hip/hip_runtime.h>
#include <hip/hip_bf16.h>

#define M_DIM 8192
#define N_DIM 4096
#define K_DIM 4096

using bf16x8 = __attribute__((ext_vector_type(8))) short;
using f32x4  = __attribute__((ext_vector_type(4))) float;

// ---------- fp32 -> bf16 (RNE via bit math) ----------
__device__ __forceinline__ unsigned short f2bf(float f) {
    unsigned int u = __float_as_uint(f);
    unsigned int r = u + 0x7fffu + ((u >> 16) & 1u);
    return (unsigned short)(r >> 16);
}

// Single fused conversion: x (n4x float4s) then w (n4w float4s) into ws.
__global__ void cvt_both_f32_to_bf16(const float* __restrict__ x,
                                     const float* __restrict__ w,
                                     unsigned short* __restrict__ ws,
                                     int n4x, int n4w) {
    int i = blockIdx.x * blockDim.x + threadIdx.x;
    const int stride = gridDim.x * blockDim.x;
    const int total = n4x + n4w;
    uint2* dx = reinterpret_cast<uint2*>(ws);
    uint2* dw = reinterpret_cast<uint2*>(ws) + n4x;
    for (; i < total; i += stride) {
        const bool isX = i < n4x;
        const float4* s4 = isX ? reinterpret_cast<const float4*>(x)
                               : reinterpret_cast<const float4*>(w);
        const int j = isX ? i : i - n4x;
        float4 v = s4[j];
        uint2 o;
        o.x = (unsigned)f2bf(v.x) | ((unsigned)f2bf(v.y) << 16);
        o.y = (unsigned)f2bf(v.z) | ((unsigned)f2bf(v.w) << 16);
        (isX ? dx : dw)[j] = o;
    }
}

// ---------- async global->LDS, 16B per lane ----------
__device__ __forceinline__ void gload16(const unsigned short* g, char* l) {
    __builtin_amdgcn_global_load_lds(
        (const __attribute__((address_space(1))) void*)g,
        (__attribute__((address_space(3))) void*)l, 16, 0, 0);
}

// ============================================================================
// 256x256 bf16 MFMA GEMM — round 14: R6's proven K-loop (best: 224.7 us)
// + LDS-transposed epilogue with 1KB-segment nontemporal stores.
// (Round 13 failed to compile: __builtin_nontemporal_store rejects HIP's
// struct float4; fixed by using the ext_vector f32x4.)
//
// K-loop (verbatim R6): per tile t (buf=t&1, X=B0(t) regs, Y=B0(t+1) regs):
//  I1: stage A1(t+1)->nbuf ; read bv1<-B1(t)      ; MFMA q00 (av=A0, X); bar
//  I2: stage A0(t+2)->buf  ; MFMA q01 (av=A0,bv1) ; read av<-A1(t); vmcnt(6) bar
//  I3: stage B0(t+2)->buf  ; read Y<-B0(t+1)      ; MFMA q11 (av=A1,bv1); bar
//  I4: stage B1(t+2)->buf  ; MFMA q10 (av=A1, X)  ; read av<-A0(t+1); vmcnt(6) bar
// (ledger + slot-death audit in round-6 notes; refcheck'd rounds 6,8,12.)
//
// Epilogue: old path stored 128 scalar dwords/thread in 64B segments (16-lane
// row runs of the 16x16 C/D layout) -> ~half-efficiency HBM writes ~11us/block.
// New: per 64-row quarter Q, the 4 waves with wm==Q>>1 write acc(+bias) to
// ldsF[64][260] (pad 260: 2-way write aliasing = free), barrier, all 512
// threads read f32x4 and store nontemporal — a wave covers ONE row => 1KB
// contiguous segment per store instruction. 4 quarters. Runs after full
// vmcnt/lgkm drain + barrier: no ledger interaction.
// ============================================================================
__global__ __launch_bounds__(512, 2) void gemm_bf16_256_8ph(
        const unsigned short* __restrict__ xb,   // [M,K] bf16 bits
        const unsigned short* __restrict__ wb,   // [N,K] bf16 bits
        const float* __restrict__ bias,          // [N]
        float* __restrict__ out) {               // [M,N]
    extern __shared__ char lds[];
    char* ldsA = lds;           // [2 buf][2 q][16384 B]
    char* ldsB = lds + 65536;   // [2 buf][2 p][16384 B]

    // L2-aware XCD chunk map (round 4: FETCH 549->201 MB)
    const int bid = blockIdx.x;
    const int xcd = bid & 7;
    const int c   = bid >> 3;                 // 0..63
    const int tm  = (xcd >> 1) * 8 + (c & 7); // 0..31
    const int tn  = (xcd & 1) * 8 + (c >> 3); // 0..15
    const int r0 = tm * 256;
    const int c0 = tn * 256;

    const int tid  = threadIdx.x;
    const int lane = tid & 63;
    const int wave = tid >> 6;        // 0..7
    const int wm = wave >> 2;         // 0..1  (128-row half)
    const int wn = wave & 3;          // 0..3  (64-col strip)
    const int lr = lane & 15;
    const int t4 = lane >> 4;

    // --- ds_read offsets (bytes within one 16KB region), T2-swizzled ---
    int aRd[4][2], bRd[2][2];
    const int swz = (lr & 7) << 4;
#pragma unroll
    for (int ks = 0; ks < 2; ++ks) {
        const int cb = (ks * 64 + t4 * 16) ^ swz;
#pragma unroll
        for (int m = 0; m < 4; ++m)
            aRd[m][ks] = (wm * 64 + m * 16 + lr) * 128 + cb;
#pragma unroll
        for (int n = 0; n < 2; ++n)
            bRd[n][ks] = (wn * 32 + n * 16 + lr) * 128 + cb;
    }

    // --- staging: wave-uniform LDS dest (HW adds lane*16), inverse-swizzled
    //     global source ---
    const int rowInBlk = lane >> 3;                       // 0..7
    const int sChunk   = ((lane & 7) ^ rowInBlk) * 8;     // element offset
    int aSrcB[2], bSrcB[2], dstOff[2];
#pragma unroll
    for (int l = 0; l < 2; ++l) {
        const int R0 = wave * 16 + l * 8;                 // lds row base 0..120
        aSrcB[l] = (r0 + (R0 >> 6) * 128 + (R0 & 63) + rowInBlk) * K_DIM + sChunk;
        bSrcB[l] = (c0 + (R0 >> 5) * 64  + (R0 & 31) + rowInBlk) * K_DIM + sChunk;
        dstOff[l] = R0 * 128;                             // wave-uniform
    }

    auto STAGE_A = [&](int q, int kt, int nb) {
#pragma unroll
        for (int l = 0; l < 2; ++l)
            gload16(xb + aSrcB[l] + q * 64 * K_DIM + kt * 64,
                    ldsA + nb * 32768 + q * 16384 + dstOff[l]);
    };
    auto STAGE_B = [&](int p, int kt, int nb) {
#pragma unroll
        for (int l = 0; l < 2; ++l)
            gload16(wb + bSrcB[l] + p * 32 * K_DIM + kt * 64,
                    ldsB + nb * 32768 + p * 16384 + dstOff[l]);
    };

    f32x4 acc[8][4];
#pragma unroll
    for (int i = 0; i < 8; ++i)
#pragma unroll
        for (int j = 0; j < 4; ++j)
            acc[i][j] = (f32x4){0.f, 0.f, 0.f, 0.f};

    bf16x8 av[4][2], bvA[2][2], bvB[2][2], bv1[2][2];

#define MFMA_QUAD(M0, N0, BV)                                                  \
    do {                                                                       \
        __builtin_amdgcn_s_setprio(1);                                         \
        _Pragma("unroll") for (int m = 0; m < 4; ++m)                          \
        _Pragma("unroll") for (int n = 0; n < 2; ++n)                          \
        _Pragma("unroll") for (int ks = 0; ks < 2; ++ks)                       \
            acc[(M0) + m][(N0) + n] = __builtin_amdgcn_mfma_f32_16x16x32_bf16( \
                av[m][ks], BV[n][ks], acc[(M0) + m][(N0) + n], 0, 0, 0);       \
        __builtin_amdgcn_s_setprio(0);                                         \
    } while (0)

#define LOAD_A(Q, BUF)                                                         \
    _Pragma("unroll") for (int m = 0; m < 4; ++m)                              \
    _Pragma("unroll") for (int ks = 0; ks < 2; ++ks)                           \
        av[m][ks] = *(const bf16x8*)(ldsA + (BUF) * 32768 + (Q) * 16384 + aRd[m][ks]);

#define LOAD_B(P, BUF, BV)                                                     \
    _Pragma("unroll") for (int n = 0; n < 2; ++n)                              \
    _Pragma("unroll") for (int ks = 0; ks < 2; ++ks)                           \
        BV[n][ks] = *(const bf16x8*)(ldsB + (BUF) * 32768 + (P) * 16384 + bRd[n][ks]);

    const int NT = K_DIM / 64;   // 64

#define TILE_BODY(T, BUF, XV, YV)                                              \
    do {                                                                       \
        const int nb_  = (BUF) ^ 1;                                           \
        const int kt1_ = ((T) + 1) & (NT - 1);                                 \
        const int kt2_ = ((T) + 2) & (NT - 1);                                 \
        /* I1: MFMA q00 (av=A0, X); read B1(t) */                              \
        STAGE_A(1, kt1_, nb_);                                                 \
        LOAD_B(1, (BUF), bv1);                                                 \
        MFMA_QUAD(0, 0, XV);                                                   \
        asm volatile("s_barrier" ::: "memory");                                \
        /* I2: MFMA q01 (av=A0, bv1); then overlay-read av<-A1(t) */           \
        STAGE_A(0, kt2_, (BUF));                                               \
        MFMA_QUAD(0, 2, bv1);                                                  \
        LOAD_A(1, (BUF));                                                      \
        asm volatile("s_waitcnt vmcnt(6)\n\ts_barrier" ::: "memory");          \
        /* I3: MFMA q11 (av=A1, bv1); read Y<-B0(t+1) */                       \
        STAGE_B(0, kt2_, (BUF));                                               \
        LOAD_B(0, nb_, YV);                                                    \
        MFMA_QUAD(4, 2, bv1);                                                  \
        asm volatile("s_barrier" ::: "memory");                                \
        /* I4: MFMA q10 (av=A1, X); then overlay-read av<-A0(t+1) */           \
        STAGE_B(1, kt2_, (BUF));                                               \
        MFMA_QUAD(4, 0, XV);                                                   \
        LOAD_A(0, nb_);                                                        \
        asm volatile("s_waitcnt vmcnt(6)\n\ts_barrier" ::: "memory");          \
    } while (0)

    // --- prologue: t0 full + t1 {A0,B0,B1}; land t0; pre-read A0(0), B0(0) ---
    STAGE_A(0, 0, 0);
    STAGE_B(0, 0, 0);
    STAGE_B(1, 0, 0);
    STAGE_A(1, 0, 0);
    STAGE_A(0, 1, 1);
    STAGE_B(0, 1, 1);
    STAGE_B(1, 1, 1);
    asm volatile("s_waitcnt vmcnt(6)\n\ts_barrier" ::: "memory");
    LOAD_A(0, 0);          // av  <- A0(0)
    LOAD_B(0, 0, bvA);     // bvA <- B0(0)

    for (int tt = 0; tt < NT / 2; ++tt) {
        TILE_BODY(2 * tt,     0, bvA, bvB);
        TILE_BODY(2 * tt + 1, 1, bvB, bvA);
    }
    // full drain before LDS reuse (in-flight dummy stages + dead ds_reads)
    asm volatile("s_waitcnt vmcnt(0) lgkmcnt(0)" ::: "memory");
    __syncthreads();

    // --- epilogue: LDS transpose -> 1KB-segment nontemporal stores ---
    // acc[mi][ni] maps to row = wm*128 + (mi>>2)*64 + (mi&3)*16 + t4*4 + j,
    //                     col = wn*64 + (ni>>1)*32 + (ni&1)*16 + lr.
    float* ldsF = (float*)lds;               // [64][260] f32 = 66.6 KB
    const int FS = 260;                      // pad: 260%32=4 -> 2-way writes
    float bvs[4];
#pragma unroll
    for (int ni = 0; ni < 4; ++ni)
        bvs[ni] = bias[c0 + wn * 64 + (ni >> 1) * 32 + (ni & 1) * 16 + lr];

#pragma unroll
    for (int Q = 0; Q < 4; ++Q) {
        if (wm == (Q >> 1)) {
#pragma unroll
            for (int miL = 0; miL < 4; ++miL) {
                const int mi = (Q & 1) * 4 + miL;
#pragma unroll
                for (int ni = 0; ni < 4; ++ni) {
                    const int col  = wn * 64 + (ni >> 1) * 32 + (ni & 1) * 16 + lr;
                    const int lrow = miL * 16 + t4 * 4;
#pragma unroll
                    for (int j = 0; j < 4; ++j)
                        ldsF[(lrow + j) * FS + col] = acc[mi][ni][j] + bvs[ni];
                }
            }
        }
        __syncthreads();
        // stores: wave covers one row per iteration -> 1KB contiguous segment
        const int rowQ = r0 + (Q >> 1) * 128 + (Q & 1) * 64;
#pragma unroll
        for (int it = 0; it < 8; ++it) {
            const int lrow = wave + 8 * it;          // 0..63
            const f32x4 v = *(const f32x4*)&ldsF[lrow * FS + lane * 4];
            __builtin_nontemporal_store(
                v, (f32x4*)&out[(size_t)(rowQ + lrow) * N_DIM + c0 + lane * 4]);
        }
        __syncthreads();   // protect ldsF before next quarter's writes
    }
#undef TILE_BODY
#undef MFMA_QUAD
#undef LOAD_A
#undef LOAD_B
}

// ============================================================================
// Proven round-1 128x128 kernel — runtime fallback if dynamic LDS
// cannot be enabled.
// ============================================================================
__global__ __launch_bounds__(256) void gemm_bf16_mfma(
        const unsigned short* __restrict__ xb,
        const unsigned short* __restrict__ wb,
        const float* __restrict__ bias,
        float* __restrict__ out) {
    __shared__ unsigned short sA[128 * 64];
    __shared__ unsigned short sB[128 * 64];

    const int nwg = (M_DIM / 128) * (N_DIM / 128);
    const int q = nwg / 8;
    int bid = blockIdx.x;
    int bid2 = (bid & 7) * q + (bid >> 3);
    const int tm = bid2 & 63;
    const int tn = bid2 >> 6;
    const int r0 = tm * 128;
    const int c0 = tn * 128;

    const int tid  = threadIdx.x;
    const int lane = tid & 63;
    const int wave = tid >> 6;
    const int wr = wave >> 1;
    const int wc = wave & 1;
    const int lr = lane & 15;
    const int t  = lane >> 4;

    int aoff[2][4], boff[2][4];
#pragma unroll
    for (int m = 0; m < 4; ++m) {
        int rowA = wr * 64 + m * 16 + lr;
        int swA  = (rowA & 7) << 4;
        int rowB = wc * 64 + m * 16 + lr;
        int swB  = (rowB & 7) << 4;
#pragma unroll
        for (int kk = 0; kk < 2; ++kk) {
            int cb = kk * 64 + t * 16;
            aoff[kk][m] = rowA * 64 + ((cb ^ swA) >> 1);
            boff[kk][m] = rowB * 64 + ((cb ^ swB) >> 1);
        }
    }

    const int sRow   = lane >> 3;
    const int sChunk = (lane & 7) ^ sRow;
    int aSrc[4], bSrc[4];
    char* ldsA[4];
    char* ldsB[4];
#pragma unroll
    for (int r = 0; r < 4; ++r) {
        int row = r * 32 + wave * 8 + sRow;
        aSrc[r] = (r0 + row) * K_DIM + sChunk * 8;
        bSrc[r] = (c0 + row) * K_DIM + sChunk * 8;
        ldsA[r] = (char*)sA + (r * 4 + wave) * 1024;
        ldsB[r] = (char*)sB + (r * 4 + wave) * 1024;
    }

    f32x4 acc[4][4];
#pragma unroll
    for (int m = 0; m < 4; ++m)
#pragma unroll
        for (int n = 0; n < 4; ++n)
            acc[m][n] = (f32x4){0.f, 0.f, 0.f, 0.f};

    for (int kt = 0; kt < K_DIM / 64; ++kt) {
        const int ko = kt * 64;
#pragma unroll
        for (int r = 0; r < 4; ++r) {
            gload16(xb + aSrc[r] + ko, ldsA[r]);
            gload16(wb + bSrc[r] + ko, ldsB[r]);
        }
        __syncthreads();
#pragma unroll
        for (int kk = 0; kk < 2; ++kk) {
            bf16x8 av[4], bv[4];
#pragma unroll
            for (int m = 0; m < 4; ++m)
                av[m] = *reinterpret_cast<const bf16x8*>(sA + aoff[kk][m]);
#pragma unroll
            for (int n = 0; n < 4; ++n)
                bv[n] = *reinterpret_cast<const bf16x8*>(sB + boff[kk][n]);
#pragma unroll
            for (int m = 0; m < 4; ++m)
#pragma unroll
                for (int n = 0; n < 4; ++n)
                    acc[m][n] = __builtin_amdgcn_mfma_f32_16x16x32_bf16(
                        av[m], bv[n], acc[m][n], 0, 0, 0);
        }
        __syncthreads();
    }

#pragma unroll
    for (int n = 0; n < 4; ++n) {
        const int col = c0 + wc * 64 + n * 16 + lr;
        const float bv = bias[col];
#pragma unroll
        for (int m = 0; m < 4; ++m) {
            const int row0 = r0 + wr * 64 + m * 16 + t * 4;
#pragma unroll
            for (int j = 0; j < 4; ++j)
                out[(row0 + j) * N_DIM + col] = acc[m][n][j] + bv;
        }
    }
}

// ---------- fp32 fallback (only if ws too small) ----------
__global__ void fallback_gemm_f32(const float* __restrict__ x,
                                  const float* __restrict__ w,
                                  const float* __restrict__ bias,
                                  float* __restrict__ out) {
    __shared__ float sX[2][4096];
    const int tid = threadIdx.x;
    const int col = blockIdx.x * 256 + tid;
    const int row0 = blockIdx.y * 2;
    for (int i = tid * 4; i < 8192; i += 1024) {
        int r = i >> 12, c = i & 4095;
        *(float4*)&sX[r][c] = *(const float4*)&x[(size_t)(row0 + r) * 4096 + c];
    }
    __syncthreads();
    const float4* wrow = (const float4*)&w[(size_t)col * 4096];
    float a0 = 0.f, a1 = 0.f;
    for (int k4 = 0; k4 < 1024; ++k4) {
        float4 wv = wrow[k4];
        int k = k4 << 2;
        a0 += wv.x * sX[0][k] + wv.y * sX[0][k + 1] + wv.z * sX[0][k + 2] + wv.w * sX[0][k + 3];
        a1 += wv.x * sX[1][k] + wv.y * sX[1][k + 1] + wv.z * sX[1][k + 2] + wv.w * sX[1][k + 3];
    }
    float bv = bias[col];
    out[(size_t)row0 * 4096 + col] = a0 + bv;
    out[(size_t)(row0 + 1) * 4096 + col] = a1 + bv;
}

extern "C" void kernel_launch(void* const* d_in, const int* in_sizes, int n_in,
                              void* d_out, int out_size, void* d_ws, size_t ws_size,
                              hipStream_t stream) {
    const float* x    = (const float*)d_in[0];
    const float* w    = (const float*)d_in[1];
    const float* bias = (const float*)d_in[2];
    float* out = (float*)d_out;

    const size_t nX = (size_t)M_DIM * K_DIM;
    const size_t nW = (size_t)N_DIM * K_DIM;
    const size_t need = (nX + nW) * sizeof(unsigned short);

    if (ws_size >= need) {
        unsigned short* xb = (unsigned short*)d_ws;
        unsigned short* wb = xb + nX;
        cvt_both_f32_to_bf16<<<3072, 256, 0, stream>>>(
            x, w, (unsigned short*)d_ws, (int)(nX / 4), (int)(nW / 4));
        hipError_t e = hipFuncSetAttribute(
            (const void*)gemm_bf16_256_8ph,
            hipFuncAttributeMaxDynamicSharedMemorySize, 131072);
        if (e == hipSuccess) {
            gemm_bf16_256_8ph<<<(M_DIM / 256) * (N_DIM / 256), 512, 131072, stream>>>(
                xb, wb, bias, out);
        } else {
            gemm_bf16_mfma<<<(M_DIM / 128) * (N_DIM / 128), 256, 0, stream>>>(
                xb, wb, bias, out);
        }
    } else {
        fallback_gemm_f32<<<dim3(N_DIM / 256, M_DIM / 2), 256, 0, stream>>>(x, w, bias, out);
    }
}

// Round 15
// 245.295 us; speedup vs baseline: 4.0524x; 1.0219x over previous
//
#include <hip/hip_runtime.h>
#include <hip/hip_bf16.h>

#define M_DIM 8192
#define N_DIM 4096
#define K_DIM 4096

using bf16x8 = __attribute__((ext_vector_type(8))) short;
using f32x4  = __attribute__((ext_vector_type(4))) float;

// ---------- fp32 -> bf16 (RNE via bit math) ----------
__device__ __forceinline__ unsigned short f2bf(float f) {
    unsigned int u = __float_as_uint(f);
    unsigned int r = u + 0x7fffu + ((u >> 16) & 1u);
    return (unsigned short)(r >> 16);
}

// Single fused conversion: x (n4x float4s) then w (n4w float4s) into ws.
__global__ void cvt_both_f32_to_bf16(const float* __restrict__ x,
                                     const float* __restrict__ w,
                                     unsigned short* __restrict__ ws,
                                     int n4x, int n4w) {
    int i = blockIdx.x * blockDim.x + threadIdx.x;
    const int stride = gridDim.x * blockDim.x;
    const int total = n4x + n4w;
    uint2* dx = reinterpret_cast<uint2*>(ws);
    uint2* dw = reinterpret_cast<uint2*>(ws) + n4x;
    for (; i < total; i += stride) {
        const bool isX = i < n4x;
        const float4* s4 = isX ? reinterpret_cast<const float4*>(x)
                               : reinterpret_cast<const float4*>(w);
        const int j = isX ? i : i - n4x;
        float4 v = s4[j];
        uint2 o;
        o.x = (unsigned)f2bf(v.x) | ((unsigned)f2bf(v.y) << 16);
        o.y = (unsigned)f2bf(v.z) | ((unsigned)f2bf(v.w) << 16);
        (isX ? dx : dw)[j] = o;
    }
}

// ---------- async global->LDS, 16B per lane ----------
__device__ __forceinline__ void gload16(const unsigned short* g, char* l) {
    __builtin_amdgcn_global_load_lds(
        (const __attribute__((address_space(1))) void*)g,
        (__attribute__((address_space(3))) void*)l, 16, 0, 0);
}

// ============================================================================
// 256x256 bf16 MFMA GEMM — round 15: R14 minus s_setprio (single-variable
// ablation). T5 is structure-conditional per the guide (m190: negative on
// barrier-lockstep GEMM; m218b: positive on role-split 8-phase). Our phases
// are lockstep; hypothesis: setprio(1) starves the co-resident wave's
// ds_read/stage issue during MFMA bursts -> late barrier arrival -> skew.
//
// K-loop (R6, proven): per tile t (buf=t&1, X=B0(t) regs, Y=B0(t+1) regs):
//  I1: stage A1(t+1)->nbuf ; read bv1<-B1(t)      ; MFMA q00 (av=A0, X); bar
//  I2: stage A0(t+2)->buf  ; MFMA q01 (av=A0,bv1) ; read av<-A1(t); vmcnt(6) bar
//  I3: stage B0(t+2)->buf  ; read Y<-B0(t+1)      ; MFMA q11 (av=A1,bv1); bar
//  I4: stage B1(t+2)->buf  ; MFMA q10 (av=A1, X)  ; read av<-A0(t+1); vmcnt(6) bar
// (ledger + slot-death audit in round-6 notes; refcheck'd rounds 6,8,12,14.)
//
// Epilogue (R14, proven): LDS-transposed 1KB-segment nontemporal stores;
// WRITE_SIZE 170->133 MB.
// ============================================================================
__global__ __launch_bounds__(512, 2) void gemm_bf16_256_8ph(
        const unsigned short* __restrict__ xb,   // [M,K] bf16 bits
        const unsigned short* __restrict__ wb,   // [N,K] bf16 bits
        const float* __restrict__ bias,          // [N]
        float* __restrict__ out) {               // [M,N]
    extern __shared__ char lds[];
    char* ldsA = lds;           // [2 buf][2 q][16384 B]
    char* ldsB = lds + 65536;   // [2 buf][2 p][16384 B]

    // L2-aware XCD chunk map (round 4: FETCH 549->201 MB)
    const int bid = blockIdx.x;
    const int xcd = bid & 7;
    const int c   = bid >> 3;                 // 0..63
    const int tm  = (xcd >> 1) * 8 + (c & 7); // 0..31
    const int tn  = (xcd & 1) * 8 + (c >> 3); // 0..15
    const int r0 = tm * 256;
    const int c0 = tn * 256;

    const int tid  = threadIdx.x;
    const int lane = tid & 63;
    const int wave = tid >> 6;        // 0..7
    const int wm = wave >> 2;         // 0..1  (128-row half)
    const int wn = wave & 3;          // 0..3  (64-col strip)
    const int lr = lane & 15;
    const int t4 = lane >> 4;

    // --- ds_read offsets (bytes within one 16KB region), T2-swizzled ---
    int aRd[4][2], bRd[2][2];
    const int swz = (lr & 7) << 4;
#pragma unroll
    for (int ks = 0; ks < 2; ++ks) {
        const int cb = (ks * 64 + t4 * 16) ^ swz;
#pragma unroll
        for (int m = 0; m < 4; ++m)
            aRd[m][ks] = (wm * 64 + m * 16 + lr) * 128 + cb;
#pragma unroll
        for (int n = 0; n < 2; ++n)
            bRd[n][ks] = (wn * 32 + n * 16 + lr) * 128 + cb;
    }

    // --- staging: wave-uniform LDS dest (HW adds lane*16), inverse-swizzled
    //     global source ---
    const int rowInBlk = lane >> 3;                       // 0..7
    const int sChunk   = ((lane & 7) ^ rowInBlk) * 8;     // element offset
    int aSrcB[2], bSrcB[2], dstOff[2];
#pragma unroll
    for (int l = 0; l < 2; ++l) {
        const int R0 = wave * 16 + l * 8;                 // lds row base 0..120
        aSrcB[l] = (r0 + (R0 >> 6) * 128 + (R0 & 63) + rowInBlk) * K_DIM + sChunk;
        bSrcB[l] = (c0 + (R0 >> 5) * 64  + (R0 & 31) + rowInBlk) * K_DIM + sChunk;
        dstOff[l] = R0 * 128;                             // wave-uniform
    }

    auto STAGE_A = [&](int q, int kt, int nb) {
#pragma unroll
        for (int l = 0; l < 2; ++l)
            gload16(xb + aSrcB[l] + q * 64 * K_DIM + kt * 64,
                    ldsA + nb * 32768 + q * 16384 + dstOff[l]);
    };
    auto STAGE_B = [&](int p, int kt, int nb) {
#pragma unroll
        for (int l = 0; l < 2; ++l)
            gload16(wb + bSrcB[l] + p * 32 * K_DIM + kt * 64,
                    ldsB + nb * 32768 + p * 16384 + dstOff[l]);
    };

    f32x4 acc[8][4];
#pragma unroll
    for (int i = 0; i < 8; ++i)
#pragma unroll
        for (int j = 0; j < 4; ++j)
            acc[i][j] = (f32x4){0.f, 0.f, 0.f, 0.f};

    bf16x8 av[4][2], bvA[2][2], bvB[2][2], bv1[2][2];

// R15: no setprio — pure MFMA burst, co-resident wave issues freely.
#define MFMA_QUAD(M0, N0, BV)                                                  \
    do {                                                                       \
        _Pragma("unroll") for (int m = 0; m < 4; ++m)                          \
        _Pragma("unroll") for (int n = 0; n < 2; ++n)                          \
        _Pragma("unroll") for (int ks = 0; ks < 2; ++ks)                       \
            acc[(M0) + m][(N0) + n] = __builtin_amdgcn_mfma_f32_16x16x32_bf16( \
                av[m][ks], BV[n][ks], acc[(M0) + m][(N0) + n], 0, 0, 0);       \
    } while (0)

#define LOAD_A(Q, BUF)                                                         \
    _Pragma("unroll") for (int m = 0; m < 4; ++m)                              \
    _Pragma("unroll") for (int ks = 0; ks < 2; ++ks)                           \
        av[m][ks] = *(const bf16x8*)(ldsA + (BUF) * 32768 + (Q) * 16384 + aRd[m][ks]);

#define LOAD_B(P, BUF, BV)                                                     \
    _Pragma("unroll") for (int n = 0; n < 2; ++n)                              \
    _Pragma("unroll") for (int ks = 0; ks < 2; ++ks)                           \
        BV[n][ks] = *(const bf16x8*)(ldsB + (BUF) * 32768 + (P) * 16384 + bRd[n][ks]);

    const int NT = K_DIM / 64;   // 64

#define TILE_BODY(T, BUF, XV, YV)                                              \
    do {                                                                       \
        const int nb_  = (BUF) ^ 1;                                           \
        const int kt1_ = ((T) + 1) & (NT - 1);                                 \
        const int kt2_ = ((T) + 2) & (NT - 1);                                 \
        /* I1: MFMA q00 (av=A0, X); read B1(t) */                              \
        STAGE_A(1, kt1_, nb_);                                                 \
        LOAD_B(1, (BUF), bv1);                                                 \
        MFMA_QUAD(0, 0, XV);                                                   \
        asm volatile("s_barrier" ::: "memory");                                \
        /* I2: MFMA q01 (av=A0, bv1); then overlay-read av<-A1(t) */           \
        STAGE_A(0, kt2_, (BUF));                                               \
        MFMA_QUAD(0, 2, bv1);                                                  \
        LOAD_A(1, (BUF));                                                      \
        asm volatile("s_waitcnt vmcnt(6)\n\ts_barrier" ::: "memory");          \
        /* I3: MFMA q11 (av=A1, bv1); read Y<-B0(t+1) */                       \
        STAGE_B(0, kt2_, (BUF));                                               \
        LOAD_B(0, nb_, YV);                                                    \
        MFMA_QUAD(4, 2, bv1);                                                  \
        asm volatile("s_barrier" ::: "memory");                                \
        /* I4: MFMA q10 (av=A1, X); then overlay-read av<-A0(t+1) */           \
        STAGE_B(1, kt2_, (BUF));                                               \
        MFMA_QUAD(4, 0, XV);                                                   \
        LOAD_A(0, nb_);                                                        \
        asm volatile("s_waitcnt vmcnt(6)\n\ts_barrier" ::: "memory");          \
    } while (0)

    // --- prologue: t0 full + t1 {A0,B0,B1}; land t0; pre-read A0(0), B0(0) ---
    STAGE_A(0, 0, 0);
    STAGE_B(0, 0, 0);
    STAGE_B(1, 0, 0);
    STAGE_A(1, 0, 0);
    STAGE_A(0, 1, 1);
    STAGE_B(0, 1, 1);
    STAGE_B(1, 1, 1);
    asm volatile("s_waitcnt vmcnt(6)\n\ts_barrier" ::: "memory");
    LOAD_A(0, 0);          // av  <- A0(0)
    LOAD_B(0, 0, bvA);     // bvA <- B0(0)

    for (int tt = 0; tt < NT / 2; ++tt) {
        TILE_BODY(2 * tt,     0, bvA, bvB);
        TILE_BODY(2 * tt + 1, 1, bvB, bvA);
    }
    // full drain before LDS reuse (in-flight dummy stages + dead ds_reads)
    asm volatile("s_waitcnt vmcnt(0) lgkmcnt(0)" ::: "memory");
    __syncthreads();

    // --- epilogue: LDS transpose -> 1KB-segment nontemporal stores ---
    // acc[mi][ni] maps to row = wm*128 + (mi>>2)*64 + (mi&3)*16 + t4*4 + j,
    //                     col = wn*64 + (ni>>1)*32 + (ni&1)*16 + lr.
    float* ldsF = (float*)lds;               // [64][260] f32 = 66.6 KB
    const int FS = 260;                      // pad: 260%32=4 -> 2-way writes
    float bvs[4];
#pragma unroll
    for (int ni = 0; ni < 4; ++ni)
        bvs[ni] = bias[c0 + wn * 64 + (ni >> 1) * 32 + (ni & 1) * 16 + lr];

#pragma unroll
    for (int Q = 0; Q < 4; ++Q) {
        if (wm == (Q >> 1)) {
#pragma unroll
            for (int miL = 0; miL < 4; ++miL) {
                const int mi = (Q & 1) * 4 + miL;
#pragma unroll
                for (int ni = 0; ni < 4; ++ni) {
                    const int col  = wn * 64 + (ni >> 1) * 32 + (ni & 1) * 16 + lr;
                    const int lrow = miL * 16 + t4 * 4;
#pragma unroll
                    for (int j = 0; j < 4; ++j)
                        ldsF[(lrow + j) * FS + col] = acc[mi][ni][j] + bvs[ni];
                }
            }
        }
        __syncthreads();
        // stores: wave covers one row per iteration -> 1KB contiguous segment
        const int rowQ = r0 + (Q >> 1) * 128 + (Q & 1) * 64;
#pragma unroll
        for (int it = 0; it < 8; ++it) {
            const int lrow = wave + 8 * it;          // 0..63
            const f32x4 v = *(const f32x4*)&ldsF[lrow * FS + lane * 4];
            __builtin_nontemporal_store(
                v, (f32x4*)&out[(size_t)(rowQ + lrow) * N_DIM + c0 + lane * 4]);
        }
        __syncthreads();   // protect ldsF before next quarter's writes
    }
#undef TILE_BODY
#undef MFMA_QUAD
#undef LOAD_A
#undef LOAD_B
}

// ============================================================================
// Proven round-1 128x128 kernel — runtime fallback if dynamic LDS
// cannot be enabled.
// ============================================================================
__global__ __launch_bounds__(256) void gemm_bf16_mfma(
        const unsigned short* __restrict__ xb,
        const unsigned short* __restrict__ wb,
        const float* __restrict__ bias,
        float* __restrict__ out) {
    __shared__ unsigned short sA[128 * 64];
    __shared__ unsigned short sB[128 * 64];

    const int nwg = (M_DIM / 128) * (N_DIM / 128);
    const int q = nwg / 8;
    int bid = blockIdx.x;
    int bid2 = (bid & 7) * q + (bid >> 3);
    const int tm = bid2 & 63;
    const int tn = bid2 >> 6;
    const int r0 = tm * 128;
    const int c0 = tn * 128;

    const int tid  = threadIdx.x;
    const int lane = tid & 63;
    const int wave = tid >> 6;
    const int wr = wave >> 1;
    const int wc = wave & 1;
    const int lr = lane & 15;
    const int t  = lane >> 4;

    int aoff[2][4], boff[2][4];
#pragma unroll
    for (int m = 0; m < 4; ++m) {
        int rowA = wr * 64 + m * 16 + lr;
        int swA  = (rowA & 7) << 4;
        int rowB = wc * 64 + m * 16 + lr;
        int swB  = (rowB & 7) << 4;
#pragma unroll
        for (int kk = 0; kk < 2; ++kk) {
            int cb = kk * 64 + t * 16;
            aoff[kk][m] = rowA * 64 + ((cb ^ swA) >> 1);
            boff[kk][m] = rowB * 64 + ((cb ^ swB) >> 1);
        }
    }

    const int sRow   = lane >> 3;
    const int sChunk = (lane & 7) ^ sRow;
    int aSrc[4], bSrc[4];
    char* ldsA[4];
    char* ldsB[4];
#pragma unroll
    for (int r = 0; r < 4; ++r) {
        int row = r * 32 + wave * 8 + sRow;
        aSrc[r] = (r0 + row) * K_DIM + sChunk * 8;
        bSrc[r] = (c0 + row) * K_DIM + sChunk * 8;
        ldsA[r] = (char*)sA + (r * 4 + wave) * 1024;
        ldsB[r] = (char*)sB + (r * 4 + wave) * 1024;
    }

    f32x4 acc[4][4];
#pragma unroll
    for (int m = 0; m < 4; ++m)
#pragma unroll
        for (int n = 0; n < 4; ++n)
            acc[m][n] = (f32x4){0.f, 0.f, 0.f, 0.f};

    for (int kt = 0; kt < K_DIM / 64; ++kt) {
        const int ko = kt * 64;
#pragma unroll
        for (int r = 0; r < 4; ++r) {
            gload16(xb + aSrc[r] + ko, ldsA[r]);
            gload16(wb + bSrc[r] + ko, ldsB[r]);
        }
        __syncthreads();
#pragma unroll
        for (int kk = 0; kk < 2; ++kk) {
            bf16x8 av[4], bv[4];
#pragma unroll
            for (int m = 0; m < 4; ++m)
                av[m] = *reinterpret_cast<const bf16x8*>(sA + aoff[kk][m]);
#pragma unroll
            for (int n = 0; n < 4; ++n)
                bv[n] = *reinterpret_cast<const bf16x8*>(sB + boff[kk][n]);
#pragma unroll
            for (int m = 0; m < 4; ++m)
#pragma unroll
                for (int n = 0; n < 4; ++n)
                    acc[m][n] = __builtin_amdgcn_mfma_f32_16x16x32_bf16(
                        av[m], bv[n], acc[m][n], 0, 0, 0);
        }
        __syncthreads();
    }

#pragma unroll
    for (int n = 0; n < 4; ++n) {
        const int col = c0 + wc * 64 + n * 16 + lr;
        const float bv = bias[col];
#pragma unroll
        for (int m = 0; m < 4; ++m) {
            const int row0 = r0 + wr * 64 + m * 16 + t * 4;
#pragma unroll
            for (int j = 0; j < 4; ++j)
                out[(row0 + j) * N_DIM + col] = acc[m][n][j] + bv;
        }
    }
}

// ---------- fp32 fallback (only if ws too small) ----------
__global__ void fallback_gemm_f32(const float* __restrict__ x,
                                  const float* __restrict__ w,
                                  const float* __restrict__ bias,
                                  float* __restrict__ out) {
    __shared__ float sX[2][4096];
    const int tid = threadIdx.x;
    const int col = blockIdx.x * 256 + tid;
    const int row0 = blockIdx.y * 2;
    for (int i = tid * 4; i < 8192; i += 1024) {
        int r = i >> 12, c = i & 4095;
        *(float4*)&sX[r][c] = *(const float4*)&x[(size_t)(row0 + r) * 4096 + c];
    }
    __syncthreads();
    const float4* wrow = (const float4*)&w[(size_t)col * 4096];
    float a0 = 0.f, a1 = 0.f;
    for (int k4 = 0; k4 < 1024; ++k4) {
        float4 wv = wrow[k4];
        int k = k4 << 2;
        a0 += wv.x * sX[0][k] + wv.y * sX[0][k + 1] + wv.z * sX[0][k + 2] + wv.w * sX[0][k + 3];
        a1 += wv.x * sX[1][k] + wv.y * sX[1][k + 1] + wv.z * sX[1][k + 2] + wv.w * sX[1][k + 3];
    }
    float bv = bias[col];
    out[(size_t)row0 * 4096 + col] = a0 + bv;
    out[(size_t)(row0 + 1) * 4096 + col] = a1 + bv;
}

extern "C" void kernel_launch(void* const* d_in, const int* in_sizes, int n_in,
                              void* d_out, int out_size, void* d_ws, size_t ws_size,
                              hipStream_t stream) {
    const float* x    = (const float*)d_in[0];
    const float* w    = (const float*)d_in[1];
    const float* bias = (const float*)d_in[2];
    float* out = (float*)d_out;

    const size_t nX = (size_t)M_DIM * K_DIM;
    const size_t nW = (size_t)N_DIM * K_DIM;
    const size_t need = (nX + nW) * sizeof(unsigned short);

    if (ws_size >= need) {
        unsigned short* xb = (unsigned short*)d_ws;
        unsigned short* wb = xb + nX;
        cvt_both_f32_to_bf16<<<3072, 256, 0, stream>>>(
            x, w, (unsigned short*)d_ws, (int)(nX / 4), (int)(nW / 4));
        hipError_t e = hipFuncSetAttribute(
            (const void*)gemm_bf16_256_8ph,
            hipFuncAttributeMaxDynamicSharedMemorySize, 131072);
        if (e == hipSuccess) {
            gemm_bf16_256_8ph<<<(M_DIM / 256) * (N_DIM / 256), 512, 131072, stream>>>(
                xb, wb, bias, out);
        } else {
            gemm_bf16_mfma<<<(M_DIM / 128) * (N_DIM / 128), 256, 0, stream>>>(
                xb, wb, bias, out);
        }
    } else {
        fallback_gemm_f32<<<dim3(N_DIM / 256, M_DIM / 2), 256, 0, stream>>>(x, w, bias, out);
    }
}